// Round 1
// baseline (47942.072 us; speedup 1.0000x reference)
//
#include <hip/hip_runtime.h>
#include <cstdint>
#include <cstddef>

// Problem constants (T, B, I, H, L) = (2048, 64, 256, 256, 2)
#define T_STEPS 2048
#define BB 64
#define II 256
#define HH 256
#define GG 1024   // 4*H gate rows
#define RING 256  // ring depth (steps) for gate buffers; power of 2

static_assert((RING & (RING - 1)) == 0, "RING must be power of 2");

typedef _Float16 half2_t __attribute__((ext_vector_type(2)));
typedef unsigned u32x4_t __attribute__((ext_vector_type(4)));

static __device__ __forceinline__ float sigm(float x) {
    return 1.0f / (1.0f + __expf(-x));
}
static __device__ __forceinline__ float tanhfast(float x) {
    float e = __expf(2.0f * x);
    return 1.0f - 2.0f / (e + 1.0f);
}
static __device__ __forceinline__ float fd2(unsigned hu, unsigned wu, float acc) {
    union { unsigned u; half2_t v; } a, b;
    a.u = hu; b.u = wu;
    return __builtin_amdgcn_fdot2(a.v, b.v, acc, false);
}

// device-scope (agent) atomics for cross-XCD producer/consumer flags.
// acquire-load emits the L1/L2 invalidate needed to observe remote ring writes;
// release-store emits waitcnt + L2 writeback so teammates' ordinary stores
// (drained by the preceding __syncthreads) become agent-visible.
static __device__ __forceinline__ int aload_acq(const int* p) {
    return __hip_atomic_load((int*)p, __ATOMIC_ACQUIRE, __HIP_MEMORY_SCOPE_AGENT);
}
static __device__ __forceinline__ void astore_rel(int* p, int v) {
    __hip_atomic_store(p, v, __ATOMIC_RELEASE, __HIP_MEMORY_SCOPE_AGENT);
}

// ---------------- weight prep (tiny) ----------------

// W (1024 x 256 f32, row-major) -> transposed f16-pair layout:
// uint4 array indexed [p4 * 1024 + row], component c = packed pair
// (W[row][2p], W[row][2p+1]) with p = 4*p4 + c. Works for W_hh and W_ih
// alike (both 1024x256 here since I == H == 256).
__global__ void k_pack_whh(const float* __restrict__ W, unsigned* __restrict__ wt) {
    int p = blockIdx.x;      // 0..127 (k-pair index)
    int row = threadIdx.x;   // 0..1023 (gate row)
    float2 v = *(const float2*)(W + (size_t)row * HH + 2 * p);
    union { unsigned u; half2_t h; } cv;
    cv.h = half2_t{ (_Float16)v.x, (_Float16)v.y };
    wt[((size_t)(p >> 2) * 1024 + row) * 4 + (p & 3)] = cv.u;
}

__global__ void k_bias_sum(const float* __restrict__ a, const float* __restrict__ b,
                           float* __restrict__ o) {
    int i = threadIdx.x;  // 1024 threads, 1 block
    o[i] = a[i] + b[i];
}

__global__ void k_init_prog(int* __restrict__ p) {
    p[threadIdx.x] = 0;  // 256 threads: prog[4][64]
}

// ---------------- shared matvec core ----------------
// gates[r0], gates[r1] = dot(hbuf(256 f16), W[row]) with W split:
// k-pairs 0..95 in VGPRs (wr0/wr1), k-pairs 96..127 in LDS (wsh).
static __device__ __forceinline__ void matvec_core(
    const u32x4_t* __restrict__ hsh, const u32x4_t* __restrict__ wsh,
    const unsigned* __restrict__ wr0, const unsigned* __restrict__ wr1,
    int r0, int r1, float& s0, float& s1)
{
    float a00 = 0.f, a01 = 0.f, a02 = 0.f, a03 = 0.f;
    float a10 = 0.f, a11 = 0.f, a12 = 0.f, a13 = 0.f;
#pragma unroll
    for (int j = 0; j < 24; ++j) {
        u32x4_t hv = hsh[j];  // broadcast (same addr across wave)
        a00 = fd2(hv.x, wr0[4 * j + 0], a00);
        a01 = fd2(hv.y, wr0[4 * j + 1], a01);
        a02 = fd2(hv.z, wr0[4 * j + 2], a02);
        a03 = fd2(hv.w, wr0[4 * j + 3], a03);
        a10 = fd2(hv.x, wr1[4 * j + 0], a10);
        a11 = fd2(hv.y, wr1[4 * j + 1], a11);
        a12 = fd2(hv.z, wr1[4 * j + 2], a12);
        a13 = fd2(hv.w, wr1[4 * j + 3], a13);
    }
#pragma unroll
    for (int j = 0; j < 8; ++j) {
        u32x4_t hv = hsh[24 + j];
        u32x4_t w0 = wsh[j * 1024 + r0];  // consecutive lanes -> conflict-free
        u32x4_t w1 = wsh[j * 1024 + r1];
        a00 = fd2(hv.x, w0.x, a00);
        a01 = fd2(hv.y, w0.y, a01);
        a02 = fd2(hv.z, w0.z, a02);
        a03 = fd2(hv.w, w0.w, a03);
        a10 = fd2(hv.x, w1.x, a10);
        a11 = fd2(hv.y, w1.y, a11);
        a12 = fd2(hv.z, w1.z, a12);
        a13 = fd2(hv.w, w1.w, a13);
    }
    s0 = (a00 + a01) + (a02 + a03);
    s1 = (a10 + a11) + (a12 + a13);
}

// ---------------- fused 4-stage pipeline ----------------
// 256 blocks = 4 stages x 64 batches; stage = blockIdx.x>>6, b = blockIdx.x&63.
//   stage0 (proj0): gx0[t] = W_ih0 @ x[t]  + bsum0           (no recurrence)
//   stage1 (lstm0): h0[t]  = LSTMCell(gx0[t], h)             (W_hh0)
//   stage2 (proj1): gx1[t] = W_ih1 @ h0[t] + bsum1           (no recurrence)
//   stage3 (lstm1): out[t] = LSTMCell(gx1[t], h)             (W_hh1)
// gx0/gx1 are RING-deep ring buffers; h0 is full-T (64 MB f16). Progress
// flags prog[stage][b] use agent-scope release/acquire. Proj stages run
// ahead until ring back-pressure caps them (~RING steps), so lstm stages'
// flag checks are register-cache hits in steady state.
__global__ __launch_bounds__(512)
__attribute__((amdgpu_waves_per_eu(2, 2)))
void k_pipe(const float* __restrict__ x,      // (T,B,I) f32
            const float* __restrict__ mask,   // (T,B)
            const float* __restrict__ reset,  // (T,B)
            const u32x4_t* __restrict__ wih0,
            const u32x4_t* __restrict__ whh0,
            const u32x4_t* __restrict__ wih1,
            const u32x4_t* __restrict__ whh1,
            const float* __restrict__ bsum0,
            const float* __restrict__ bsum1,
            _Float16* __restrict__ gx0,       // [RING][B][1024]
            _Float16* __restrict__ gx1,       // [RING][B][1024]
            _Float16* __restrict__ h0s,       // [T][B][256]
            float* __restrict__ out,          // (T,B,H) f32
            float* __restrict__ hn,           // (2,B,H)
            float* __restrict__ cn,           // (2,B,H)
            int* __restrict__ prog)           // [4][B]
{
    __shared__ __align__(16) u32x4_t wsh[8 * 1024];  // 128 KiB weight slice
    __shared__ __align__(16) _Float16 hbuf[HH];      // 512 B input vector
    __shared__ float gbF[256];                        // sigm(f) crossover
    __shared__ float gbO[256];                        // sigm(o) crossover

    const int stage = blockIdx.x >> 6;
    const int b = blockIdx.x & 63;
    const int tid = threadIdx.x;
    const int r0 = tid, r1 = tid + 512;

    const u32x4_t* w4 = (stage == 0) ? wih0 : (stage == 1) ? whh0
                      : (stage == 2) ? wih1 : whh1;

    // stage LDS weight slice (quads 24..31), once
#pragma unroll
    for (int j = 0; j < 8; ++j) {
        wsh[j * 1024 + r0] = w4[(24 + j) * 1024 + r0];
        wsh[j * 1024 + r1] = w4[(24 + j) * 1024 + r1];
    }
    // register-resident slice (quads 0..23), pinned via asm fences so the
    // allocator cannot rematerialize the loads inside the t-loop
    unsigned wr0[96], wr1[96];
#pragma unroll
    for (int j = 0; j < 24; ++j) {
        u32x4_t a = w4[j * 1024 + r0];
        u32x4_t c = w4[j * 1024 + r1];
        wr0[4 * j + 0] = a.x; wr0[4 * j + 1] = a.y; wr0[4 * j + 2] = a.z; wr0[4 * j + 3] = a.w;
        wr1[4 * j + 0] = c.x; wr1[4 * j + 1] = c.y; wr1[4 * j + 2] = c.z; wr1[4 * j + 3] = c.w;
    }
#pragma unroll
    for (int j = 0; j < 96; ++j) {
        asm volatile("" : "+v"(wr0[j]));
        asm volatile("" : "+v"(wr1[j]));
    }

    const u32x4_t* hsh = (const u32x4_t*)hbuf;

    if (stage == 0) {
        // ---- proj0: x -> gx0 ring ----
        const float bs0 = bsum0[r0], bs1 = bsum0[r1];
        if (tid < HH) hbuf[tid] = (_Float16)x[(size_t)b * II + tid];  // t=0
        int bp = 0;
        int* mf = prog + 0 * BB + b;
        const int* cf = prog + 1 * BB + b;
        __syncthreads();
        for (int t = 0; t < T_STEPS; ++t) {
            float xn = 0.f;  // prefetch next x (pure input, always available)
            if (tid < HH && t + 1 < T_STEPS)
                xn = x[((size_t)(t + 1) * BB + b) * II + tid];
            float s0, s1;
            matvec_core(hsh, wsh, wr0, wr1, r0, r1, s0, s1);
            s0 += bs0; s1 += bs1;
            // ring back-pressure vs lstm0 (rarely fires; cached)
            if (t + 1 - bp > RING - 4) {
                bp = aload_acq(cf);
                while (t + 1 - bp > RING - 4) { __builtin_amdgcn_s_sleep(4); bp = aload_acq(cf); }
            }
            size_t ro = ((size_t)(t & (RING - 1)) * BB + b) * GG;
            gx0[ro + r0] = (_Float16)s0;
            gx0[ro + r1] = (_Float16)s1;
            __syncthreads();                       // drains vmem -> stores in L2
            if (tid == 0) astore_rel(mf, t + 1);   // wb L2 + publish
            if (tid < HH) hbuf[tid] = (_Float16)xn;
            __syncthreads();
        }
    } else if (stage == 1 || stage == 3) {
        // ---- lstm stage: gx ring + own recurrence -> h0s (L0) / out (L1) ----
        const int L1f = (stage == 3);
        const _Float16* gxin = L1f ? gx1 : gx0;
        const int* sf = prog + (stage - 1) * BB + b;  // source: proj stage
        int* mf = prog + stage * BB + b;
        if (tid < HH) hbuf[tid] = (_Float16)0.f;
        float hp = 0.f, cp = 0.f;
        int seen = 0;
        __syncthreads();
        for (int t = 0; t < T_STEPS; ++t) {
            if (seen <= t) {  // wait for gx[t] (steady state: cache hit, no atomic)
                seen = aload_acq(sf);
                while (seen <= t) { __builtin_amdgcn_s_sleep(1); seen = aload_acq(sf); }
            }
            size_t ro = ((size_t)(t & (RING - 1)) * BB + b) * GG;
            // issued at step top, consumed at step end -> latency hidden
            float g0 = (float)gxin[ro + r0];
            float g1 = (float)gxin[ro + r1];
            float mc = mask[(size_t)t * BB + b];
            float rc = reset[(size_t)t * BB + b];
            float s0, s1;
            matvec_core(hsh, wsh, wr0, wr1, r0, r1, s0, s1);
            s0 += g0; s1 += g1;  // row r0: i (tid<256) or f ; row r1: g or o
            if (tid >= HH) { gbF[tid - HH] = sigm(s0); gbO[tid - HH] = sigm(s1); }
            __syncthreads();
            if (tid < HH) {
                float i_ = sigm(s0), g_ = tanhfast(s1);
                float f_ = gbF[tid], o_ = gbO[tid];
                float cnew = f_ * cp + i_ * g_;
                float hnew = o_ * tanhfast(cnew);
                float hb = hnew * mc + hp * (1.f - mc);
                float cb = cnew * mc + cp * (1.f - mc);
                if (L1f) out[(size_t)t * (BB * HH) + (size_t)b * HH + tid] = hb;
                else     h0s[((size_t)t * BB + b) * HH + tid] = (_Float16)hb;
                hp = hb * (1.f - rc);
                cp = cb * (1.f - rc);
                hbuf[tid] = (_Float16)hp;
            }
            __syncthreads();                       // drains h0s/out stores too
            if (tid == 0) astore_rel(mf, t + 1);
        }
        if (tid < HH) {
            hn[((size_t)L1f * BB + b) * HH + tid] = hp;
            cn[((size_t)L1f * BB + b) * HH + tid] = cp;
        }
    } else {
        // ---- proj1: h0s -> gx1 ring ----
        const float bs0 = bsum1[r0], bs1 = bsum1[r1];
        int seen = 0, bp = 0;
        const int* sf = prog + 1 * BB + b;
        const int* cf = prog + 3 * BB + b;
        int* mf = prog + 2 * BB + b;
        __syncthreads();
        for (int t = 0; t < T_STEPS; ++t) {
            if (seen <= t) {
                seen = aload_acq(sf);
                while (seen <= t) { __builtin_amdgcn_s_sleep(1); seen = aload_acq(sf); }
            }
            if (tid < HH) hbuf[tid] = h0s[((size_t)t * BB + b) * HH + tid];
            __syncthreads();
            float s0, s1;
            matvec_core(hsh, wsh, wr0, wr1, r0, r1, s0, s1);
            s0 += bs0; s1 += bs1;
            if (t + 1 - bp > RING - 4) {  // back-pressure vs lstm1
                bp = aload_acq(cf);
                while (t + 1 - bp > RING - 4) { __builtin_amdgcn_s_sleep(4); bp = aload_acq(cf); }
            }
            size_t ro = ((size_t)(t & (RING - 1)) * BB + b) * GG;
            gx1[ro + r0] = (_Float16)s0;
            gx1[ro + r1] = (_Float16)s1;
            __syncthreads();
            if (tid == 0) astore_rel(mf, t + 1);
        }
    }
}

// ---------------- host ----------------
extern "C" void kernel_launch(void* const* d_in, const int* in_sizes, int n_in,
                              void* d_out, int out_size, void* d_ws, size_t ws_size,
                              hipStream_t stream) {
    (void)in_sizes; (void)n_in; (void)out_size; (void)ws_size;
    const float* input = (const float*)d_in[0];
    const float* maskp = (const float*)d_in[1];
    const float* resetp = (const float*)d_in[2];
    const float* Wih0 = (const float*)d_in[3];
    const float* Whh0 = (const float*)d_in[4];
    const float* bih0 = (const float*)d_in[5];
    const float* bhh0 = (const float*)d_in[6];
    const float* Wih1 = (const float*)d_in[7];
    const float* Whh1 = (const float*)d_in[8];
    const float* bih1 = (const float*)d_in[9];
    const float* bhh1 = (const float*)d_in[10];

    // workspace layout (~130 MiB total; f16 path previously needed 258 MiB, so fits)
    const size_t WPACK = (size_t)GG * HH * 2;  // 512 KiB per packed matrix
    char* p = (char*)d_ws;
    unsigned* wih0t = (unsigned*)p; p += WPACK;
    unsigned* whh0t = (unsigned*)p; p += WPACK;
    unsigned* wih1t = (unsigned*)p; p += WPACK;
    unsigned* whh1t = (unsigned*)p; p += WPACK;
    float* bsum0 = (float*)p; p += GG * sizeof(float);
    float* bsum1 = (float*)p; p += GG * sizeof(float);
    int* prog = (int*)p; p += 4096;
    _Float16* gx0 = (_Float16*)p; p += (size_t)RING * BB * GG * 2;  // 32 MiB
    _Float16* gx1 = (_Float16*)p; p += (size_t)RING * BB * GG * 2;  // 32 MiB
    _Float16* h0s = (_Float16*)p; p += (size_t)T_STEPS * BB * HH * 2;  // 64 MiB

    float* out1 = (float*)d_out;                     // (T,B,H)
    float* hn = out1 + (size_t)T_STEPS * BB * HH;    // (2,B,H)
    float* cn = hn + 2 * (size_t)BB * HH;            // (2,B,H)

    // weight prep (all tiny)
    k_pack_whh<<<dim3(HH / 2), 1024, 0, stream>>>(Wih0, wih0t);
    k_pack_whh<<<dim3(HH / 2), 1024, 0, stream>>>(Whh0, whh0t);
    k_pack_whh<<<dim3(HH / 2), 1024, 0, stream>>>(Wih1, wih1t);
    k_pack_whh<<<dim3(HH / 2), 1024, 0, stream>>>(Whh1, whh1t);
    k_bias_sum<<<dim3(1), GG, 0, stream>>>(bih0, bhh0, bsum0);
    k_bias_sum<<<dim3(1), GG, 0, stream>>>(bih1, bhh1, bsum1);
    k_init_prog<<<dim3(1), 256, 0, stream>>>(prog);  // flags MUST reset each launch

    const float* a_x = input; const float* a_m = maskp; const float* a_r = resetp;
    const u32x4_t* a_w0 = (const u32x4_t*)wih0t;
    const u32x4_t* a_w1 = (const u32x4_t*)whh0t;
    const u32x4_t* a_w2 = (const u32x4_t*)wih1t;
    const u32x4_t* a_w3 = (const u32x4_t*)whh1t;
    const float* a_b0 = bsum0; const float* a_b1 = bsum1;
    _Float16* a_g0 = gx0; _Float16* a_g1 = gx1; _Float16* a_h0 = h0s;
    float* a_out = out1; float* a_hn = hn; float* a_cn = cn; int* a_pr = prog;
    void* args[] = { &a_x, &a_m, &a_r, &a_w0, &a_w1, &a_w2, &a_w3, &a_b0, &a_b1,
                     &a_g0, &a_g1, &a_h0, &a_out, &a_hn, &a_cn, &a_pr };

    // cooperative launch guarantees all 256 blocks (4 stages x 64 batches)
    // are co-resident (1 WG/CU on 256 CUs). Fallback plain launch is benign
    // on a full-chip part: 256 WGs dispatch immediately to 256 idle CUs.
    hipError_t err = hipLaunchCooperativeKernel((const void*)k_pipe, dim3(4 * BB),
                                                dim3(512), args, 0, stream);
    if (err != hipSuccess) {
        (void)hipGetLastError();
        k_pipe<<<dim3(4 * BB), dim3(512), 0, stream>>>(
            a_x, a_m, a_r, a_w0, a_w1, a_w2, a_w3, a_b0, a_b1,
            a_g0, a_g1, a_h0, a_out, a_hn, a_cn, a_pr);
    }
}

// Round 2
// 8268.489 us; speedup vs baseline: 5.7982x; 5.7982x over previous
//
#include <hip/hip_runtime.h>
#include <cstdint>
#include <cstddef>

// Problem constants (T, B, I, H, L) = (2048, 64, 256, 256, 2)
#define T_STEPS 2048
#define BB 64
#define II 256
#define HH 256
#define GG 1024   // 4*H gate rows
#define RING 64   // ring depth (steps); power of 2
#define VQ 23     // weight k-pair-quads resident in registers
#define LQ 9      // weight k-pair-quads resident in LDS (VQ+LQ == 32)

static_assert((RING & (RING - 1)) == 0, "RING must be power of 2");
static_assert(VQ + LQ == 32, "full K coverage");

typedef _Float16 half2_t __attribute__((ext_vector_type(2)));
typedef unsigned u32x4_t __attribute__((ext_vector_type(4)));

static __device__ __forceinline__ float sigm(float x) {
    return 1.0f / (1.0f + __expf(-x));
}
static __device__ __forceinline__ float tanhfast(float x) {
    float e = __expf(2.0f * x);
    return 1.0f - 2.0f / (e + 1.0f);
}
static __device__ __forceinline__ float fd2(unsigned hu, unsigned wu, float acc) {
    union { unsigned u; half2_t v; } a, b;
    a.u = hu; b.u = wu;
    return __builtin_amdgcn_fdot2(a.v, b.v, acc, false);
}

// RELAXED agent-scope atomics: coherent across XCDs (routed to MALL) with NO
// buffer_inv / buffer_wbl2 — the L2-wiping acquire/release of round 1 was the
// catastrophe amplifier. Ordering: producers rely on __syncthreads() (compiler
// drains vmcnt(0) before s_barrier) between data stores and the flag store.
static __device__ __forceinline__ unsigned aloadu(const unsigned* p) {
    return __hip_atomic_load((unsigned*)p, __ATOMIC_RELAXED, __HIP_MEMORY_SCOPE_AGENT);
}
static __device__ __forceinline__ void astoreu(unsigned* p, unsigned v) {
    __hip_atomic_store(p, v, __ATOMIC_RELAXED, __HIP_MEMORY_SCOPE_AGENT);
}
static __device__ __forceinline__ int aloadi(const int* p) {
    return __hip_atomic_load((int*)p, __ATOMIC_RELAXED, __HIP_MEMORY_SCOPE_AGENT);
}
static __device__ __forceinline__ void astorei(int* p, int v) {
    __hip_atomic_store(p, v, __ATOMIC_RELAXED, __HIP_MEMORY_SCOPE_AGENT);
}
#define CFENCE asm volatile("" ::: "memory")

// ---------------- weight prep (tiny) ----------------
// W (1024 x 256 f32, row-major) -> transposed f16-pair layout:
// uint4 array indexed [p4 * 1024 + row], component c = packed pair
// (W[row][2p], W[row][2p+1]) with p = 4*p4 + c. Works for W_ih and W_hh
// alike (both 1024x256 since I == H == 256).
__global__ void k_pack_w(const float* __restrict__ W, unsigned* __restrict__ wt) {
    int p = blockIdx.x;      // 0..127 (k-pair index)
    int row = threadIdx.x;   // 0..1023 (gate row)
    float2 v = *(const float2*)(W + (size_t)row * HH + 2 * p);
    union { unsigned u; half2_t h; } cv;
    cv.h = half2_t{ (_Float16)v.x, (_Float16)v.y };
    wt[((size_t)(p >> 2) * 1024 + row) * 4 + (p & 3)] = cv.u;
}

__global__ void k_bias_sum(const float* __restrict__ a, const float* __restrict__ b,
                           float* __restrict__ o) {
    int i = threadIdx.x;  // 1024 threads, 1 block
    o[i] = a[i] + b[i];
}

__global__ void k_init_prog(int* __restrict__ p) {
    p[threadIdx.x] = 0;  // 256 threads: prog[4][64]
}

// ---------------- fused 4-stage pipeline ----------------
// 256 blocks = 4 stages x 64 batches; 256 threads/block, 4 gate rows/thread:
// rows (tid, tid+256, tid+512, tid+768) = (i, f, g, o) of h-dim tid — the
// whole LSTM tail is thread-local (no LDS gate crossover, 1 barrier/step).
// 1 wave/SIMD (waves_per_eu(1,1)) frees the full unified register file:
// 368 weight dwords/thread resident (23 quads x 4 rows) + 9 quads in LDS.
__global__ __launch_bounds__(256, 1)
__attribute__((amdgpu_waves_per_eu(1, 1)))
void k_pipe(const float* __restrict__ x,      // (T,B,I) f32
            const float* __restrict__ mask,   // (T,B)
            const float* __restrict__ reset,  // (T,B)
            const u32x4_t* __restrict__ wih0,
            const u32x4_t* __restrict__ whh0,
            const u32x4_t* __restrict__ wih1,
            const u32x4_t* __restrict__ whh1,
            const float* __restrict__ bsum0,
            const float* __restrict__ bsum1,
            unsigned* __restrict__ gx0,       // [RING][B][512] u32 (f16 gate pairs)
            unsigned* __restrict__ gx1,       // [RING][B][512] u32
            unsigned* __restrict__ h0r,       // [RING][B][256] u32 (f32 h bits)
            float* __restrict__ out,          // (T,B,H) f32
            float* __restrict__ hn,           // (2,B,H)
            float* __restrict__ cn,           // (2,B,H)
            int* __restrict__ prog)           // [4][B]
{
    __shared__ __align__(16) u32x4_t wsh[LQ * 1024];  // 144 KiB weight slice
    __shared__ __align__(16) _Float16 hbuf[2][HH];    // double-buffered input vec

    const int stage = blockIdx.x >> 6;
    const int b = blockIdx.x & 63;
    const int tid = threadIdx.x;
    const int r0 = tid, r1 = tid + 256, r2 = tid + 512, r3 = tid + 768;

    const u32x4_t* w4 = (stage == 0) ? wih0 : (stage == 1) ? whh0
                      : (stage == 2) ? wih1 : whh1;

    // stage LDS weight slice (quads VQ..31), once
#pragma unroll
    for (int j = 0; j < LQ; ++j) {
        wsh[j * 1024 + r0] = w4[(size_t)(VQ + j) * 1024 + r0];
        wsh[j * 1024 + r1] = w4[(size_t)(VQ + j) * 1024 + r1];
        wsh[j * 1024 + r2] = w4[(size_t)(VQ + j) * 1024 + r2];
        wsh[j * 1024 + r3] = w4[(size_t)(VQ + j) * 1024 + r3];
    }
    // register-resident slice (quads 0..VQ-1), pinned vs rematerialization
    unsigned wr0[4 * VQ], wr1[4 * VQ], wr2[4 * VQ], wr3[4 * VQ];
#pragma unroll
    for (int j = 0; j < VQ; ++j) {
        u32x4_t q;
        q = w4[(size_t)j * 1024 + r0]; wr0[4*j] = q.x; wr0[4*j+1] = q.y; wr0[4*j+2] = q.z; wr0[4*j+3] = q.w;
        q = w4[(size_t)j * 1024 + r1]; wr1[4*j] = q.x; wr1[4*j+1] = q.y; wr1[4*j+2] = q.z; wr1[4*j+3] = q.w;
        q = w4[(size_t)j * 1024 + r2]; wr2[4*j] = q.x; wr2[4*j+1] = q.y; wr2[4*j+2] = q.z; wr2[4*j+3] = q.w;
        q = w4[(size_t)j * 1024 + r3]; wr3[4*j] = q.x; wr3[4*j+1] = q.y; wr3[4*j+2] = q.z; wr3[4*j+3] = q.w;
    }
#pragma unroll
    for (int j = 0; j < 4 * VQ; ++j) {
        asm volatile("" : "+v"(wr0[j]));
        asm volatile("" : "+v"(wr1[j]));
        asm volatile("" : "+v"(wr2[j]));
        asm volatile("" : "+v"(wr3[j]));
    }

    float bs0 = 0.f, bs1 = 0.f, bs2 = 0.f, bs3 = 0.f;
    if (stage == 0 || stage == 2) {
        const float* bs = (stage == 0) ? bsum0 : bsum1;
        bs0 = bs[r0]; bs1 = bs[r1]; bs2 = bs[r2]; bs3 = bs[r3];
    }
    float hp = 0.f, cp = 0.f;

    hbuf[0][tid] = (stage == 0) ? (_Float16)x[(size_t)b * II + tid] : (_Float16)0.f;
    hbuf[1][tid] = (_Float16)0.f;

    int seen = 0, bp = 0;
    int* myf = prog + stage * BB + b;
    const int* srcf = prog + (stage > 0 ? stage - 1 : 0) * BB + b;
    const int* consf = prog + (stage < 3 ? stage + 1 : 3) * BB + b;
    __syncthreads();

    for (int t = 0; t < T_STEPS; ++t) {
        float xn = 0.f, mc = 0.f, rc = 0.f;
        unsigned gA = 0, gB = 0;

        // ---- pre-matvec (block-uniform branch) ----
        if (stage == 0) {
            if (t + 1 < T_STEPS)
                xn = x[((size_t)(t + 1) * BB + b) * II + tid];
            if (t - bp > RING - 8) {                 // ring back-pressure vs lstm0
                bp = aloadi(consf);
                while (t - bp > RING - 8) { __builtin_amdgcn_s_sleep(8); bp = aloadi(consf); }
                CFENCE;
            }
        } else if (stage == 2) {
            if (seen <= t) {                         // wait for h0[t] from lstm0
                seen = aloadi(srcf);
                while (seen <= t) { __builtin_amdgcn_s_sleep(2); seen = aloadi(srcf); }
                CFENCE;
            }
            unsigned hu = aloadu(h0r + ((size_t)(t & (RING - 1)) * BB + b) * HH + tid);
            __syncthreads();                         // barA: prev reads done + prev gx1 stores drained
            if (tid == 0) { astorei(myf, t); CFENCE; }  // publish completion of step t-1
            hbuf[0][tid] = (_Float16)__uint_as_float(hu);
            if (t - bp > RING - 8) {                 // ring back-pressure vs lstm1
                bp = aloadi(consf);
                while (t - bp > RING - 8) { __builtin_amdgcn_s_sleep(8); bp = aloadi(consf); }
                CFENCE;
            }
            __syncthreads();                         // barB: hbuf visible
        } else {
            if (seen <= t) {                         // wait for gx[t] (steady: reg-cached)
                seen = aloadi(srcf);
                while (seen <= t) { __builtin_amdgcn_s_sleep(2); seen = aloadi(srcf); }
                CFENCE;
            }
            const unsigned* gring = (stage == 1) ? gx0 : gx1;
            size_t gbase = ((size_t)(t & (RING - 1)) * BB + b) * 512;
            gA = aloadu(gring + gbase + tid);        // issued now, used after matvec
            gB = aloadu(gring + gbase + 256 + tid);
            mc = mask[(size_t)t * BB + b];
            rc = reset[(size_t)t * BB + b];
            if (stage == 1 && t - bp > RING - 8) {   // h0r ring back-pressure vs proj1
                bp = aloadi(consf);
                while (t - bp > RING - 8) { __builtin_amdgcn_s_sleep(8); bp = aloadi(consf); }
                CFENCE;
            }
        }

        // ---- matvec: 4 rows x 256 (single emission for all stages) ----
        const u32x4_t* hsh = (const u32x4_t*)((stage == 2) ? hbuf[0] : hbuf[t & 1]);
        float a00 = 0.f, a01 = 0.f, a02 = 0.f, a03 = 0.f;
        float a10 = 0.f, a11 = 0.f, a12 = 0.f, a13 = 0.f;
        float a20 = 0.f, a21 = 0.f, a22 = 0.f, a23 = 0.f;
        float a30 = 0.f, a31 = 0.f, a32 = 0.f, a33 = 0.f;
#pragma unroll
        for (int j = 0; j < VQ; ++j) {
            u32x4_t hv = hsh[j];  // broadcast (same addr across wave)
            a00 = fd2(hv.x, wr0[4*j+0], a00); a01 = fd2(hv.y, wr0[4*j+1], a01);
            a02 = fd2(hv.z, wr0[4*j+2], a02); a03 = fd2(hv.w, wr0[4*j+3], a03);
            a10 = fd2(hv.x, wr1[4*j+0], a10); a11 = fd2(hv.y, wr1[4*j+1], a11);
            a12 = fd2(hv.z, wr1[4*j+2], a12); a13 = fd2(hv.w, wr1[4*j+3], a13);
            a20 = fd2(hv.x, wr2[4*j+0], a20); a21 = fd2(hv.y, wr2[4*j+1], a21);
            a22 = fd2(hv.z, wr2[4*j+2], a22); a23 = fd2(hv.w, wr2[4*j+3], a23);
            a30 = fd2(hv.x, wr3[4*j+0], a30); a31 = fd2(hv.y, wr3[4*j+1], a31);
            a32 = fd2(hv.z, wr3[4*j+2], a32); a33 = fd2(hv.w, wr3[4*j+3], a33);
        }
#pragma unroll
        for (int j = 0; j < LQ; ++j) {
            u32x4_t hv = hsh[VQ + j];
            u32x4_t w0 = wsh[j * 1024 + r0];  // consecutive lanes -> conflict-free
            a00 = fd2(hv.x, w0.x, a00); a01 = fd2(hv.y, w0.y, a01);
            a02 = fd2(hv.z, w0.z, a02); a03 = fd2(hv.w, w0.w, a03);
            u32x4_t w1 = wsh[j * 1024 + r1];
            a10 = fd2(hv.x, w1.x, a10); a11 = fd2(hv.y, w1.y, a11);
            a12 = fd2(hv.z, w1.z, a12); a13 = fd2(hv.w, w1.w, a13);
            u32x4_t w2 = wsh[j * 1024 + r2];
            a20 = fd2(hv.x, w2.x, a20); a21 = fd2(hv.y, w2.y, a21);
            a22 = fd2(hv.z, w2.z, a22); a23 = fd2(hv.w, w2.w, a23);
            u32x4_t w3 = wsh[j * 1024 + r3];
            a30 = fd2(hv.x, w3.x, a30); a31 = fd2(hv.y, w3.y, a31);
            a32 = fd2(hv.z, w3.z, a32); a33 = fd2(hv.w, w3.w, a33);
        }
        float s0 = (a00 + a01) + (a02 + a03);  // row r0: i-gate
        float s1 = (a10 + a11) + (a12 + a13);  // row r1: f-gate
        float s2 = (a20 + a21) + (a22 + a23);  // row r2: g-gate
        float s3 = (a30 + a31) + (a32 + a33);  // row r3: o-gate

        // ---- post-matvec (block-uniform branch) ----
        if (stage == 0 || stage == 2) {
            s0 += bs0; s1 += bs1; s2 += bs2; s3 += bs3;
            unsigned* gring = (stage == 0) ? gx0 : gx1;
            size_t gbase = ((size_t)(t & (RING - 1)) * BB + b) * 512;
            union { unsigned u; half2_t h; } pa, pb;
            pa.h = half2_t{ (_Float16)s0, (_Float16)s2 };  // (i, g)
            pb.h = half2_t{ (_Float16)s1, (_Float16)s3 };  // (f, o)
            astoreu(gring + gbase + tid, pa.u);
            astoreu(gring + gbase + 256 + tid, pb.u);
            if (stage == 0) {
                hbuf[(t + 1) & 1][tid] = (_Float16)xn;
                __syncthreads();                      // drains vmcnt before barrier
                if (tid == 0) { astorei(myf, t + 1); CFENCE; }
            }
            // stage2: stores drain at next iteration's barA; flag published there
        } else {
            union { unsigned u; half2_t h; } ua, ub;
            ua.u = gA; ub.u = gB;
            float si = s0 + (float)ua.h.x;
            float sf = s1 + (float)ub.h.x;
            float sg = s2 + (float)ua.h.y;
            float so = s3 + (float)ub.h.y;
            float i_ = sigm(si), f_ = sigm(sf), g_ = tanhfast(sg), o_ = sigm(so);
            float cnew = f_ * cp + i_ * g_;
            float hnew = o_ * tanhfast(cnew);
            float hb = hnew * mc + hp * (1.f - mc);
            float cb = cnew * mc + cp * (1.f - mc);
            if (stage == 1)
                astoreu(h0r + ((size_t)(t & (RING - 1)) * BB + b) * HH + tid,
                        __float_as_uint(hb));
            else
                out[(size_t)t * (BB * HH) + (size_t)b * HH + tid] = hb;
            hp = hb * (1.f - rc);
            cp = cb * (1.f - rc);
            hbuf[(t + 1) & 1][tid] = (_Float16)hp;
            __syncthreads();                          // drains h0r/out stores too
            if (tid == 0) { astorei(myf, t + 1); CFENCE; }
        }
    }

    if (stage == 2) {  // publish final step for lstm1
        __syncthreads();
        if (tid == 0) { astorei(myf, T_STEPS); CFENCE; }
    }
    if (stage == 1 || stage == 3) {
        int L = (stage == 3);
        hn[((size_t)L * BB + b) * HH + tid] = hp;
        cn[((size_t)L * BB + b) * HH + tid] = cp;
    }
}

// ---------------- host ----------------
extern "C" void kernel_launch(void* const* d_in, const int* in_sizes, int n_in,
                              void* d_out, int out_size, void* d_ws, size_t ws_size,
                              hipStream_t stream) {
    (void)in_sizes; (void)n_in; (void)out_size; (void)ws_size;
    const float* input = (const float*)d_in[0];
    const float* maskp = (const float*)d_in[1];
    const float* resetp = (const float*)d_in[2];
    const float* Wih0 = (const float*)d_in[3];
    const float* Whh0 = (const float*)d_in[4];
    const float* bih0 = (const float*)d_in[5];
    const float* bhh0 = (const float*)d_in[6];
    const float* Wih1 = (const float*)d_in[7];
    const float* Whh1 = (const float*)d_in[8];
    const float* bih1 = (const float*)d_in[9];
    const float* bhh1 = (const float*)d_in[10];

    // workspace layout (~22 MiB)
    const size_t WPACK = (size_t)GG * HH * 2;  // 512 KiB per packed matrix
    char* p = (char*)d_ws;
    unsigned* wih0t = (unsigned*)p; p += WPACK;
    unsigned* whh0t = (unsigned*)p; p += WPACK;
    unsigned* wih1t = (unsigned*)p; p += WPACK;
    unsigned* whh1t = (unsigned*)p; p += WPACK;
    float* bsum0 = (float*)p; p += GG * sizeof(float);
    float* bsum1 = (float*)p; p += GG * sizeof(float);
    int* prog = (int*)p; p += 4096;
    unsigned* gx0 = (unsigned*)p; p += (size_t)RING * BB * 512 * 4;  // 8 MiB
    unsigned* gx1 = (unsigned*)p; p += (size_t)RING * BB * 512 * 4;  // 8 MiB
    unsigned* h0r = (unsigned*)p; p += (size_t)RING * BB * 256 * 4;  // 4 MiB

    float* out1 = (float*)d_out;                     // (T,B,H)
    float* hn = out1 + (size_t)T_STEPS * BB * HH;    // (2,B,H)
    float* cn = hn + 2 * (size_t)BB * HH;            // (2,B,H)

    // weight prep (all tiny)
    k_pack_w<<<dim3(HH / 2), 1024, 0, stream>>>(Wih0, wih0t);
    k_pack_w<<<dim3(HH / 2), 1024, 0, stream>>>(Whh0, whh0t);
    k_pack_w<<<dim3(HH / 2), 1024, 0, stream>>>(Wih1, wih1t);
    k_pack_w<<<dim3(HH / 2), 1024, 0, stream>>>(Whh1, whh1t);
    k_bias_sum<<<dim3(1), GG, 0, stream>>>(bih0, bhh0, bsum0);
    k_bias_sum<<<dim3(1), GG, 0, stream>>>(bih1, bhh1, bsum1);
    k_init_prog<<<dim3(1), 256, 0, stream>>>(prog);  // flags MUST reset each launch

    const float* a_x = input; const float* a_m = maskp; const float* a_r = resetp;
    const u32x4_t* a_w0 = (const u32x4_t*)wih0t;
    const u32x4_t* a_w1 = (const u32x4_t*)whh0t;
    const u32x4_t* a_w2 = (const u32x4_t*)wih1t;
    const u32x4_t* a_w3 = (const u32x4_t*)whh1t;
    const float* a_b0 = bsum0; const float* a_b1 = bsum1;
    unsigned* a_g0 = gx0; unsigned* a_g1 = gx1; unsigned* a_h0 = h0r;
    float* a_out = out1; float* a_hn = hn; float* a_cn = cn; int* a_pr = prog;
    void* args[] = { &a_x, &a_m, &a_r, &a_w0, &a_w1, &a_w2, &a_w3, &a_b0, &a_b1,
                     &a_g0, &a_g1, &a_h0, &a_out, &a_hn, &a_cn, &a_pr };

    // cooperative launch guarantees all 256 blocks (4 stages x 64 batches) are
    // co-resident (1 WG/CU). Plain-launch fallback is benign on a full 256-CU
    // part: 256 WGs dispatch immediately to 256 idle CUs.
    hipError_t err = hipLaunchCooperativeKernel((const void*)k_pipe, dim3(4 * BB),
                                                dim3(256), args, 0, stream);
    if (err != hipSuccess) {
        (void)hipGetLastError();
        k_pipe<<<dim3(4 * BB), dim3(256), 0, stream>>>(
            a_x, a_m, a_r, a_w0, a_w1, a_w2, a_w3, a_b0, a_b1,
            a_g0, a_g1, a_h0, a_out, a_hn, a_cn, a_pr);
    }
}